// Round 4
// baseline (60.581 us; speedup 1.0000x reference)
//
#include <hip/hip_runtime.h>
#include <hip/hip_bf16.h>

// Problem constants (match reference.py)
#define BB 32
#define SS 2048
#define DD 768
#define WW 1024

typedef float f32x4 __attribute__((ext_vector_type(4)));

// Kernel 1: boundary detection. One thread per (b, s) subword.
// Builds startLB[b][v] = lower_bound of v in the sorted row wid[b, :], for
// v in [0, W] (inclusive sentinel). Every entry is written exactly once per
// call (gap-filling covers empty words). Also writes mask[b][v].
__global__ __launch_bounds__(256) void boundaries_kernel(
    const int* __restrict__ wid,      // [B, S] sorted per row
    int*       __restrict__ startLB,  // [B, W+1]
    float*     __restrict__ mask)     // [B, W]
{
    const int t = blockIdx.x * 256 + threadIdx.x;   // [0, B*S)
    const int b = t >> 11;                          // / S
    const int s = t & (SS - 1);                     // % S

    const int* ids = wid + (long)b * SS;
    const int w = ids[s];
    const int p = (s == 0) ? -1 : ids[s - 1];

    int*   sl = startLB + (long)b * (WW + 1);
    float* mk = mask + (long)b * WW;

    // This thread is the unique writer for words v in (p, w].
    for (int v = p + 1; v <= w; ++v) {
        sl[v] = s;
        mk[v] = (v == w) ? 1.0f : 0.0f;   // gap words (v<w) are empty
    }
    // Tail: words beyond the last id are empty; write the sentinel.
    if (s == SS - 1) {
        for (int v = w + 1; v <= WW; ++v) {
            sl[v] = SS;
            if (v < WW) mk[v] = 0.0f;
        }
    }
}

// Kernel 2: streaming mean-pool. One wave (64 lanes) per (batch, word).
// hid/X are single-use streams -> non-temporal hints keep L1/L2 for the
// startLB table. Word index forced wave-uniform via readfirstlane so the
// range loads scalarize and loop bounds live in SGPRs.
__global__ __launch_bounds__(256) void mean_pool_words_kernel(
    const float* __restrict__ hid,      // [B, S, D]
    const int*   __restrict__ startLB,  // [B, W+1]
    float*       __restrict__ X)        // [B, W, D]
{
    const int wave = threadIdx.x >> 6;      // 0..3
    const int lane = threadIdx.x & 63;
    int gw = blockIdx.x * 4 + wave;         // global word id in [0, B*W)
    gw = __builtin_amdgcn_readfirstlane(gw);
    const int b = gw >> 10;                 // / W
    const int w = gw & (WW - 1);            // % W

    const int* sl = startLB + (long)b * (WW + 1) + w;
    const int start = __builtin_amdgcn_readfirstlane(sl[0]);
    const int end   = __builtin_amdgcn_readfirstlane(sl[1]);
    const int cnt   = end - start;

    f32x4 acc0 = (f32x4)0.0f;
    f32x4 acc1 = (f32x4)0.0f;
    f32x4 acc2 = (f32x4)0.0f;

    const f32x4* src = (const f32x4*)(hid + (long)b * SS * DD);
    for (int s = start; s < end; ++s) {
        const f32x4* row = src + (long)s * (DD / 4);
        f32x4 v0 = __builtin_nontemporal_load(row + lane);
        f32x4 v1 = __builtin_nontemporal_load(row + lane + 64);
        f32x4 v2 = __builtin_nontemporal_load(row + lane + 128);
        acc0 += v0;
        acc1 += v1;
        acc2 += v2;
    }

    const float scale = (cnt > 0) ? (1.0f / (float)cnt) : 0.0f;

    f32x4* dst = (f32x4*)(X + ((long)b * WW + w) * DD);
    f32x4 o0 = acc0 * scale;
    f32x4 o1 = acc1 * scale;
    f32x4 o2 = acc2 * scale;
    __builtin_nontemporal_store(o0, dst + lane);
    __builtin_nontemporal_store(o1, dst + lane + 64);
    __builtin_nontemporal_store(o2, dst + lane + 128);
}

extern "C" void kernel_launch(void* const* d_in, const int* in_sizes, int n_in,
                              void* d_out, int out_size, void* d_ws, size_t ws_size,
                              hipStream_t stream) {
    const float* hid = (const float*)d_in[0];   // [B,S,D] float32
    const int*   wid = (const int*)d_in[1];     // [B,S] int32

    float* X    = (float*)d_out;                // [B,W,D] flat first
    float* mask = X + (long)BB * WW * DD;       // [B,W] after it

    int* startLB = (int*)d_ws;                  // [B, W+1] = 131,200 bytes

    // Kernel 1: 64K threads, one per subword.
    boundaries_kernel<<<(BB * SS) / 256, 256, 0, stream>>>(wid, startLB, mask);

    // Kernel 2: one wave per word, 4 waves per block.
    const int n_words = BB * WW;                // 32768
    mean_pool_words_kernel<<<n_words / 4, 256, 0, stream>>>(hid, startLB, X);
}

// Round 5
// 59.255 us; speedup vs baseline: 1.0224x; 1.0224x over previous
//
#include <hip/hip_runtime.h>
#include <hip/hip_bf16.h>

// Problem constants (match reference.py)
#define BB 32
#define SS 2048
#define DD 768
#define WW 1024

typedef float f32x4 __attribute__((ext_vector_type(4)));

// Kernel 1: boundary detection. One thread per (b, s) subword.
// Builds startLB[b][v] = lower_bound of v in the sorted row wid[b, :], for
// v in [0, W] (inclusive sentinel). Every entry is written exactly once per
// call (gap-filling covers empty words). Also writes mask[b][v].
__global__ __launch_bounds__(256) void boundaries_kernel(
    const int* __restrict__ wid,      // [B, S] sorted per row
    int*       __restrict__ startLB,  // [B, W+1]
    float*     __restrict__ mask)     // [B, W]
{
    const int t = blockIdx.x * 256 + threadIdx.x;   // [0, B*S)
    const int b = t >> 11;                          // / S
    const int s = t & (SS - 1);                     // % S

    const int* ids = wid + (long)b * SS;
    const int w = ids[s];
    const int p = (s == 0) ? -1 : ids[s - 1];

    int*   sl = startLB + (long)b * (WW + 1);
    float* mk = mask + (long)b * WW;

    // This thread is the unique writer for words v in (p, w].
    for (int v = p + 1; v <= w; ++v) {
        sl[v] = s;
        mk[v] = (v == w) ? 1.0f : 0.0f;   // gap words (v<w) are empty
    }
    // Tail: words beyond the last id are empty; write the sentinel.
    if (s == SS - 1) {
        for (int v = w + 1; v <= WW; ++v) {
            sl[v] = SS;
            if (v < WW) mk[v] = 0.0f;
        }
    }
}

// Kernel 2: streaming mean-pool. One wave (64 lanes) per PAIR of consecutive
// (batch, word) entries. Plain (cached) loads/stores — NT hints regressed
// (R4: 57.2->60.6us). Bounds are wave-uniform via readfirstlane -> SGPRs.
// Each lane owns 3 float4 slots of each word's 768-float embedding.
__global__ __launch_bounds__(256) void mean_pool_words_kernel(
    const float* __restrict__ hid,      // [B, S, D]
    const int*   __restrict__ startLB,  // [B, W+1]
    float*       __restrict__ X)        // [B, W, D]
{
    const int wave = threadIdx.x >> 6;      // 0..3
    const int lane = threadIdx.x & 63;
    int gp = blockIdx.x * 4 + wave;         // word-pair id in [0, B*W/2)
    gp = __builtin_amdgcn_readfirstlane(gp);
    const int b  = gp >> 9;                 // / (W/2)
    const int w0 = (gp & 511) * 2;          // first word of the pair

    const int* sl = startLB + (long)b * (WW + 1) + w0;
    const int start0 = __builtin_amdgcn_readfirstlane(sl[0]);
    const int mid    = __builtin_amdgcn_readfirstlane(sl[1]);
    const int end1   = __builtin_amdgcn_readfirstlane(sl[2]);
    const int cnt0 = mid - start0;
    const int cnt1 = end1 - mid;

    f32x4 a0 = (f32x4)0.0f, a1 = (f32x4)0.0f, a2 = (f32x4)0.0f;  // word w0
    f32x4 b0 = (f32x4)0.0f, b1 = (f32x4)0.0f, b2 = (f32x4)0.0f;  // word w0+1

    const f32x4* src = (const f32x4*)(hid + (long)b * SS * DD);
    for (int s = start0; s < mid; ++s) {
        const f32x4* row = src + (long)s * (DD / 4);
        a0 += row[lane];
        a1 += row[lane + 64];
        a2 += row[lane + 128];
    }
    for (int s = mid; s < end1; ++s) {
        const f32x4* row = src + (long)s * (DD / 4);
        b0 += row[lane];
        b1 += row[lane + 64];
        b2 += row[lane + 128];
    }

    const float sc0 = (cnt0 > 0) ? (1.0f / (float)cnt0) : 0.0f;
    const float sc1 = (cnt1 > 0) ? (1.0f / (float)cnt1) : 0.0f;

    f32x4* dst = (f32x4*)(X + ((long)b * WW + w0) * DD);
    dst[lane]       = a0 * sc0;
    dst[lane + 64]  = a1 * sc0;
    dst[lane + 128] = a2 * sc0;
    dst[lane + 192] = b0 * sc1;
    dst[lane + 256] = b1 * sc1;
    dst[lane + 320] = b2 * sc1;
}

extern "C" void kernel_launch(void* const* d_in, const int* in_sizes, int n_in,
                              void* d_out, int out_size, void* d_ws, size_t ws_size,
                              hipStream_t stream) {
    const float* hid = (const float*)d_in[0];   // [B,S,D] float32
    const int*   wid = (const int*)d_in[1];     // [B,S] int32

    float* X    = (float*)d_out;                // [B,W,D] flat first
    float* mask = X + (long)BB * WW * DD;       // [B,W] after it

    int* startLB = (int*)d_ws;                  // [B, W+1] = 131,200 bytes

    // Kernel 1: 64K threads, one per subword.
    boundaries_kernel<<<(BB * SS) / 256, 256, 0, stream>>>(wid, startLB, mask);

    // Kernel 2: one wave per pair of words, 4 waves per block.
    const int n_pairs = BB * WW / 2;            // 16384
    mean_pool_words_kernel<<<n_pairs / 4, 256, 0, stream>>>(hid, startLB, X);
}

// Round 6
// 55.630 us; speedup vs baseline: 1.0890x; 1.0652x over previous
//
#include <hip/hip_runtime.h>
#include <hip/hip_bf16.h>

// Problem constants (match reference.py)
#define BB 32
#define SS 2048
#define DD 768
#define WW 1024

typedef float f32x4 __attribute__((ext_vector_type(4)));

// Kernel 1: boundary detection. One thread per (b, s) subword.
// Builds startLB[b][v] = lower_bound of v in the sorted row wid[b, :], for
// v in [0, W] (inclusive sentinel). Every entry is written exactly once per
// call (gap-filling covers empty words). Also writes mask[b][v].
__global__ __launch_bounds__(256) void boundaries_kernel(
    const int* __restrict__ wid,      // [B, S] sorted per row
    int*       __restrict__ startLB,  // [B, W+1]
    float*     __restrict__ mask)     // [B, W]
{
    const int t = blockIdx.x * 256 + threadIdx.x;   // [0, B*S)
    const int b = t >> 11;                          // / S
    const int s = t & (SS - 1);                     // % S

    const int* ids = wid + (long)b * SS;
    const int w = ids[s];
    const int p = (s == 0) ? -1 : ids[s - 1];

    int*   sl = startLB + (long)b * (WW + 1);
    float* mk = mask + (long)b * WW;

    // This thread is the unique writer for words v in (p, w].
    for (int v = p + 1; v <= w; ++v) {
        sl[v] = s;
        mk[v] = (v == w) ? 1.0f : 0.0f;   // gap words (v<w) are empty
    }
    // Tail: words beyond the last id are empty; write the sentinel.
    if (s == SS - 1) {
        for (int v = w + 1; v <= WW; ++v) {
            sl[v] = SS;
            if (v < WW) mk[v] = 0.0f;
        }
    }
}

// Kernel 2: streaming mean-pool. One wave (64 lanes) per (batch, word) —
// the round-2 structure (best measured). Unroll-by-2 with dual accumulators:
// avg cnt=2, so the common case is a straight-line 6-load burst.
__global__ __launch_bounds__(256) void mean_pool_words_kernel(
    const float* __restrict__ hid,      // [B, S, D]
    const int*   __restrict__ startLB,  // [B, W+1]
    float*       __restrict__ X)        // [B, W, D]
{
    const int wave = threadIdx.x >> 6;      // 0..3
    const int lane = threadIdx.x & 63;
    const int gw = blockIdx.x * 4 + wave;   // global word id in [0, B*W)
    const int b = gw >> 10;                 // / W
    const int w = gw & (WW - 1);            // % W

    const int* sl = startLB + (long)b * (WW + 1) + w;
    const int start = sl[0];
    const int end   = sl[1];
    const int cnt   = end - start;

    f32x4 a0 = (f32x4)0.0f, a1 = (f32x4)0.0f, a2 = (f32x4)0.0f;
    f32x4 c0 = (f32x4)0.0f, c1 = (f32x4)0.0f, c2 = (f32x4)0.0f;

    const f32x4* src = (const f32x4*)(hid + (long)b * SS * DD);
    int s = start;
    for (; s + 2 <= end; s += 2) {
        const f32x4* r0 = src + (long)s * (DD / 4);
        const f32x4* r1 = r0 + (DD / 4);
        a0 += r0[lane];
        a1 += r0[lane + 64];
        a2 += r0[lane + 128];
        c0 += r1[lane];
        c1 += r1[lane + 64];
        c2 += r1[lane + 128];
    }
    if (s < end) {
        const f32x4* r0 = src + (long)s * (DD / 4);
        a0 += r0[lane];
        a1 += r0[lane + 64];
        a2 += r0[lane + 128];
    }
    a0 += c0; a1 += c1; a2 += c2;

    const float scale = (cnt > 0) ? (1.0f / (float)cnt) : 0.0f;

    f32x4* dst = (f32x4*)(X + ((long)b * WW + w) * DD);
    dst[lane]       = a0 * scale;
    dst[lane + 64]  = a1 * scale;
    dst[lane + 128] = a2 * scale;
}

extern "C" void kernel_launch(void* const* d_in, const int* in_sizes, int n_in,
                              void* d_out, int out_size, void* d_ws, size_t ws_size,
                              hipStream_t stream) {
    const float* hid = (const float*)d_in[0];   // [B,S,D] float32
    const int*   wid = (const int*)d_in[1];     // [B,S] int32

    float* X    = (float*)d_out;                // [B,W,D] flat first
    float* mask = X + (long)BB * WW * DD;       // [B,W] after it

    int* startLB = (int*)d_ws;                  // [B, W+1] = 131,200 bytes

    // Kernel 1: 64K threads, one per subword.
    boundaries_kernel<<<(BB * SS) / 256, 256, 0, stream>>>(wid, startLB, mask);

    // Kernel 2: one wave per word, 4 waves per block.
    const int n_words = BB * WW;                // 32768
    mean_pool_words_kernel<<<n_words / 4, 256, 0, stream>>>(hid, startLB, X);
}